// Round 3
// baseline (2178.229 us; speedup 1.0000x reference)
//
#include <hip/hip_runtime.h>
#include <hip/hip_bf16.h>
#include <math.h>

// ---------------------------------------------------------------------------
// B=32, N=128, D=5000, H=256, C=4
//   1) x_tilde = x @ Er^T            (MFMA bf16 NT gemm, fp32 in/out)
//   2) Wcat = concat 6 W (d2d memcpy); P = x_tilde @ Wcat^T (one MFMA gemm)
//   3) UTb = bf16-packed transposed U
//   4) build_schedule_t: PER-TREE level schedule (32 independent schedules)
//   5) tree_scan_mfma (R10): one WG per tree, 512 thr / 8 waves, NO grid
//      sync, NO fences, NO atomics. Per level: M=16 node-tile, all 9
//      H256xH256 matvecs via mfma_f32_16x16x32_bf16 with the fp32 state
//      split into bf16 hi+lo (2 MFMAs per fragment -> fp32-accurate h side,
//      numerics match the R5 VALU body). U streamed from L2 as MFMA B
//      operands (~1.1 MB/level/CU = the per-level floor). State in plain
//      global fp32 (same-WG producer/consumer; __syncthreads drains stores).
//      Epilogue (leaf-max -> Vr logits -> softmax) fused via running max.
//   Rationale (R2 counters): scan was 31 us/level with VALUBusy 9.3% --
//      9.2k FMA/thread VALU body + full-U L2 stream per 4 nodes. MFMA cuts
//      the math ~16x; tree-parallel kills all sync cost.
// ---------------------------------------------------------------------------

#define H_DIM 256
#define N_NODES 128
#define B_TREES 32
#define LOFF_STRIDE 132

typedef short bf16x8 __attribute__((ext_vector_type(8)));
typedef float f32x4 __attribute__((ext_vector_type(4)));

__device__ __forceinline__ float sigmoidf_(float x) {
    return 1.0f / (1.0f + expf(-x));
}
__device__ __forceinline__ unsigned bfp(float x) {  // fp32 -> bf16 bits (RNE)
    unsigned u = __float_as_uint(x);
    return (u + 0x7fffu + ((u >> 16) & 1u)) >> 16;
}
__device__ __forceinline__ float u16f(unsigned short u) {
    return __uint_as_float(((unsigned)u) << 16);
}

// split fp32 -> bf16 hi + bf16 lo (x ~= hi + lo to ~2^-17 rel)
__device__ __forceinline__ void split8(const float* x, uint4& hi, uint4& lo) {
    unsigned hb[8], lb[8];
#pragma unroll
    for (int i = 0; i < 8; ++i) {
        const unsigned h = bfp(x[i]);
        const float hv = __uint_as_float(h << 16);
        hb[i] = h;
        lb[i] = bfp(x[i] - hv);
    }
    hi.x = hb[0] | (hb[1] << 16); hi.y = hb[2] | (hb[3] << 16);
    hi.z = hb[4] | (hb[5] << 16); hi.w = hb[6] | (hb[7] << 16);
    lo.x = lb[0] | (lb[1] << 16); lo.y = lb[2] | (lb[3] << 16);
    lo.z = lb[4] | (lb[5] << 16); lo.w = lb[6] | (lb[7] << 16);
}

// swizzled ushort index for [16][256] bf16 LDS tiles (XOR kills the 512B-row
// bank alias on the MFMA A-fragment ds_read_b128: 16 rows -> <=2-way, free)
__device__ __forceinline__ int sidx(int row, int h) {
    return row * 256 + (h ^ ((row & 7) << 3));
}

// ---------------------------------------------------------------------------
// MFMA bf16 NT GEMM (unchanged, verified): C[M,N] = A[M,K] @ B[N,K]^T.
// Fragment maps: A[m=lane&15][k=(lane>>4)*8+j]; C/D: row=(lane>>4)*4+reg,
// col=lane&15.
// ---------------------------------------------------------------------------
__global__ __launch_bounds__(256) void gemm_mfma_nt(
    const float* __restrict__ A, const float* __restrict__ B,
    float* __restrict__ C, int K, int ldc) {
    __shared__ short As[64][40];
    __shared__ short Bs[64][40];
    const int tid = threadIdx.x;
    const int bm = blockIdx.x, bn = blockIdx.y;
    const int row = tid >> 2;
    const int quad = tid & 3;
    const int wave = tid >> 6;
    const int lane = tid & 63;
    const int lm = lane & 15;
    const int kq = lane >> 4;

    f32x4 acc[4];
#pragma unroll
    for (int i = 0; i < 4; ++i) acc[i] = (f32x4){0.f, 0.f, 0.f, 0.f};

    const int nk = (K + 31) >> 5;
    for (int kt = 0; kt < nk; ++kt) {
        const int k0 = kt << 5;
        const int kbase = k0 + quad * 8;
        {
            float a8[8];
            const float* Ap = A + (size_t)(bm * 64 + row) * K + kbase;
            if (kbase + 8 <= K) {
                const float4 v0 = *(const float4*)Ap;
                const float4 v1 = *(const float4*)(Ap + 4);
                a8[0] = v0.x; a8[1] = v0.y; a8[2] = v0.z; a8[3] = v0.w;
                a8[4] = v1.x; a8[5] = v1.y; a8[6] = v1.z; a8[7] = v1.w;
            } else {
#pragma unroll
                for (int i = 0; i < 8; ++i)
                    a8[i] = (kbase + i < K) ? Ap[i] : 0.f;
            }
            uint4 v;
            v.x = bfp(a8[0]) | (bfp(a8[1]) << 16);
            v.y = bfp(a8[2]) | (bfp(a8[3]) << 16);
            v.z = bfp(a8[4]) | (bfp(a8[5]) << 16);
            v.w = bfp(a8[6]) | (bfp(a8[7]) << 16);
            *(uint4*)&As[row][quad * 8] = v;
        }
        {
            float b8[8];
            const float* Bp = B + (size_t)(bn * 64 + row) * K + kbase;
            if (kbase + 8 <= K) {
                const float4 v0 = *(const float4*)Bp;
                const float4 v1 = *(const float4*)(Bp + 4);
                b8[0] = v0.x; b8[1] = v0.y; b8[2] = v0.z; b8[3] = v0.w;
                b8[4] = v1.x; b8[5] = v1.y; b8[6] = v1.z; b8[7] = v1.w;
            } else {
#pragma unroll
                for (int i = 0; i < 8; ++i)
                    b8[i] = (kbase + i < K) ? Bp[i] : 0.f;
            }
            uint4 v;
            v.x = bfp(b8[0]) | (bfp(b8[1]) << 16);
            v.y = bfp(b8[2]) | (bfp(b8[3]) << 16);
            v.z = bfp(b8[4]) | (bfp(b8[5]) << 16);
            v.w = bfp(b8[6]) | (bfp(b8[7]) << 16);
            *(uint4*)&Bs[row][quad * 8] = v;
        }
        __syncthreads();
        const bf16x8 af = *(const bf16x8*)&As[wave * 16 + lm][kq * 8];
#pragma unroll
        for (int nt = 0; nt < 4; ++nt) {
            const bf16x8 bf = *(const bf16x8*)&Bs[nt * 16 + lm][kq * 8];
            acc[nt] = __builtin_amdgcn_mfma_f32_16x16x32_bf16(af, bf, acc[nt], 0, 0, 0);
        }
        __syncthreads();
    }
#pragma unroll
    for (int nt = 0; nt < 4; ++nt) {
#pragma unroll
        for (int r = 0; r < 4; ++r) {
            const int gm = bm * 64 + wave * 16 + kq * 4 + r;
            const int gn = bn * 64 + nt * 16 + lm;
            C[(size_t)gm * ldc + gn] = acc[nt][r];
        }
    }
}

// UTb[(m*32 + jblk)*256 + h] = uint4 of 8 bf16 = U_m[h][8*jblk .. 8*jblk+7]
__global__ __launch_bounds__(256) void transpose_pack_u(
    const float* __restrict__ U0, const float* __restrict__ U1,
    const float* __restrict__ U2, const float* __restrict__ U3,
    const float* __restrict__ U4, const float* __restrict__ U5,
    const float* __restrict__ U6, const float* __restrict__ U7,
    const float* __restrict__ U8, uint4* __restrict__ UTb) {
    const float* Us[9] = {U0, U1, U2, U3, U4, U5, U6, U7, U8};
    const int jb = blockIdx.x;
    const int m = blockIdx.y;
    const int h = threadIdx.x;
    const float* U = Us[m] + (size_t)h * 256 + jb * 8;
    uint4 v;
    v.x = bfp(U[0]) | (bfp(U[1]) << 16);
    v.y = bfp(U[2]) | (bfp(U[3]) << 16);
    v.z = bfp(U[4]) | (bfp(U[5]) << 16);
    v.w = bfp(U[6]) | (bfp(U[7]) << 16);
    UTb[(size_t)(m * 32 + jb) * 256 + h] = v;
}

// Per-tree level schedule: schedT[tree][pos] = local node id, loffT[tree][l].
__global__ __launch_bounds__(64) void build_schedule_t(
    const int* __restrict__ parents, int* __restrict__ schedT,
    int* __restrict__ loffT) {
    __shared__ unsigned char depth[B_TREES][N_NODES];
    __shared__ short cur[B_TREES][N_NODES + 2];
    const int t = threadIdx.x;
    if (t < B_TREES) {
        for (int l = 0; l < N_NODES + 2; ++l) cur[t][l] = 0;
        depth[t][0] = 0;
        cur[t][0] = 1;
        int maxd = 0;
        for (int i = 1; i < N_NODES; ++i) {
            const int d = depth[t][parents[t * N_NODES + i] - 1] + 1;
            depth[t][i] = (unsigned char)d;
            cur[t][d]++;
            if (d > maxd) maxd = d;
        }
        const int nl = maxd + 1;
        int acc = 0;
        for (int l = 0; l <= nl; ++l) {
            const int c = (l < nl) ? (int)cur[t][l] : 0;
            loffT[t * LOFF_STRIDE + l] = acc;
            cur[t][l] = (short)acc;   // becomes placement cursor
            acc += c;
        }
        for (int i = 0; i < N_NODES; ++i) {
            const int d = depth[t][i];
            schedT[t * N_NODES + (int)(cur[t][d]++)] = i;
        }
        loffT[t * LOFF_STRIDE + LOFF_STRIDE - 1] = nl;
    }
}

// ---------------------------------------------------------------------------
// Tree-parallel MFMA scan: 1 WG (512 thr, 8 waves) per tree; fused epilogue.
// Wave w owns output h dims [w*32, w*32+32) (2 n-tiles). Per level, nodes in
// M=16 tiles; A = state tiles (bf16 hi+lo) in swizzled LDS; B = UTb from L2.
// ---------------------------------------------------------------------------
__global__ __launch_bounds__(512, 1) void tree_scan_mfma(
    const float* __restrict__ P, const uint4* __restrict__ UTb,
    const int* __restrict__ parents,
    const int* __restrict__ schedT, const int* __restrict__ loffT,
    const int* __restrict__ is_leaf,
    const float* __restrict__ Vr, const float* __restrict__ br,
    float* __restrict__ Ssh, float* __restrict__ Sru,
    float* __restrict__ out) {
    const int tree = blockIdx.x;
    const int tid = threadIdx.x;
    const int lane = tid & 63;
    const int wave = tid >> 6;          // 0..7
    const int nt0 = wave * 2;           // global n-tile base (2 per wave)
    const int arow = lane & 15;         // A-frag row / D col
    const int kq = lane >> 4;           // 0..3

    __shared__ unsigned short t_hsp_hi[4096], t_hsp_lo[4096];
    __shared__ unsigned short t_hrp_hi[4096], t_hrp_lo[4096];
    __shared__ unsigned short t_vsh_hi[4096], t_vsh_lo[4096];
    __shared__ unsigned short t_hsh_hi[4096], t_hsh_lo[4096];
    __shared__ unsigned short t_v2_hi[4096],  t_v2_lo[4096];
    __shared__ float hm[H_DIM];
    __shared__ float lg[4];

    const int* sch = schedT + tree * N_NODES;
    const int nlev = loffT[tree * LOFF_STRIDE + LOFF_STRIDE - 1];

    float runmax0 = -3.402823466e38f;
    float runmax1 = -3.402823466e38f;

    for (int l = 0; l < nlev; ++l) {
        const int lo = loffT[tree * LOFF_STRIDE + l];
        const int hiL = loffT[tree * LOFF_STRIDE + l + 1];
        for (int t0 = lo; t0 < hiL; t0 += 16) {
            // ---- gather parent states, split hi/lo, stage to LDS ----
            {
                const int nq = tid >> 5;      // node row 0..15
                const int sg = tid & 31;      // 8-float segment
                const int h0 = sg * 8;
                const int idx = t0 + nq;
                const int ndl = (idx < hiL) ? sch[idx] : sch[t0];
                const int p = parents[tree * N_NODES + ndl];
                float hs[8], hr[8];
#pragma unroll
                for (int i = 0; i < 8; ++i) { hs[i] = 0.f; hr[i] = 0.f; }
                if (p != 0) {
                    const float* as = Ssh + ((size_t)tree * N_NODES + (p - 1)) * H_DIM + h0;
                    const float* ar = Sru + ((size_t)tree * N_NODES + (p - 1)) * H_DIM + h0;
                    const float4 a0 = *(const float4*)as;
                    const float4 a1 = *(const float4*)(as + 4);
                    const float4 b0 = *(const float4*)ar;
                    const float4 b1 = *(const float4*)(ar + 4);
                    hs[0] = a0.x; hs[1] = a0.y; hs[2] = a0.z; hs[3] = a0.w;
                    hs[4] = a1.x; hs[5] = a1.y; hs[6] = a1.z; hs[7] = a1.w;
                    hr[0] = b0.x; hr[1] = b0.y; hr[2] = b0.z; hr[3] = b0.w;
                    hr[4] = b1.x; hr[5] = b1.y; hr[6] = b1.z; hr[7] = b1.w;
                }
                uint4 vh, vl;
                const int si = sidx(nq, h0);
                split8(hs, vh, vl);
                *(uint4*)&t_hsp_hi[si] = vh;
                *(uint4*)&t_hsp_lo[si] = vl;
                split8(hr, vh, vl);
                *(uint4*)&t_hrp_hi[si] = vh;
                *(uint4*)&t_hrp_lo[si] = vl;
            }
            __syncthreads();

            // per-lane row -> node mapping (D rows = kq*4+r)
            int gnode[4]; bool vrow[4];
#pragma unroll
            for (int r = 0; r < 4; ++r) {
                const int idx = t0 + kq * 4 + r;
                vrow[r] = idx < hiL;
                gnode[r] = tree * N_NODES + (vrow[r] ? sch[idx] : sch[t0]);
            }

            // ================= stage 1: r_sh, z_sh =================
            f32x4 a_r[2], a_z[2];
#pragma unroll
            for (int nt = 0; nt < 2; ++nt) {
                a_r[nt] = (f32x4){0.f, 0.f, 0.f, 0.f};
                a_z[nt] = (f32x4){0.f, 0.f, 0.f, 0.f};
            }
#pragma unroll
            for (int ks = 0; ks < 8; ++ks) {
                const int ai = sidx(arow, ks * 32 + kq * 8);
                const bf16x8 ahi = *(const bf16x8*)&t_hsp_hi[ai];
                const bf16x8 alo = *(const bf16x8*)&t_hsp_lo[ai];
#pragma unroll
                for (int nt = 0; nt < 2; ++nt) {
                    const int hcol = (nt0 + nt) * 16 + arow;
                    const size_t jb = (size_t)(ks * 4 + kq) * 256 + hcol;
                    const bf16x8 b0 = *(const bf16x8*)(UTb + 0 * 8192 + jb);
                    const bf16x8 b1 = *(const bf16x8*)(UTb + 1 * 8192 + jb);
                    a_r[nt] = __builtin_amdgcn_mfma_f32_16x16x32_bf16(ahi, b0, a_r[nt], 0, 0, 0);
                    a_r[nt] = __builtin_amdgcn_mfma_f32_16x16x32_bf16(alo, b0, a_r[nt], 0, 0, 0);
                    a_z[nt] = __builtin_amdgcn_mfma_f32_16x16x32_bf16(ahi, b1, a_z[nt], 0, 0, 0);
                    a_z[nt] = __builtin_amdgcn_mfma_f32_16x16x32_bf16(alo, b1, a_z[nt], 0, 0, 0);
                }
            }
            float z_sh[2][4], hsp_f[2][4];
#pragma unroll
            for (int nt = 0; nt < 2; ++nt) {
#pragma unroll
                for (int r = 0; r < 4; ++r) {
                    const int mrow = kq * 4 + r;
                    const int h = (nt0 + nt) * 16 + arow;
                    const size_t pb = (size_t)gnode[r] * 1536;
                    const float pr = P[pb + h];
                    const float pz = P[pb + 256 + h];
                    const int ai = sidx(mrow, h);
                    const float hsp = u16f(t_hsp_hi[ai]) + u16f(t_hsp_lo[ai]);
                    const float rsh = sigmoidf_(pr + a_r[nt][r]);
                    const float zsh = sigmoidf_(pz + a_z[nt][r]);
                    const float vsh = hsp * rsh;
                    z_sh[nt][r] = zsh;
                    hsp_f[nt][r] = hsp;
                    const unsigned hb = bfp(vsh);
                    t_vsh_hi[ai] = (unsigned short)hb;
                    t_vsh_lo[ai] = (unsigned short)bfp(vsh - __uint_as_float(hb << 16));
                }
            }
            __syncthreads();

            // ================= stage 2: h_sh =================
            f32x4 a_h[2];
#pragma unroll
            for (int nt = 0; nt < 2; ++nt) a_h[nt] = (f32x4){0.f, 0.f, 0.f, 0.f};
#pragma unroll
            for (int ks = 0; ks < 8; ++ks) {
                const int ai = sidx(arow, ks * 32 + kq * 8);
                const bf16x8 ahi = *(const bf16x8*)&t_vsh_hi[ai];
                const bf16x8 alo = *(const bf16x8*)&t_vsh_lo[ai];
#pragma unroll
                for (int nt = 0; nt < 2; ++nt) {
                    const int hcol = (nt0 + nt) * 16 + arow;
                    const size_t jb = (size_t)(ks * 4 + kq) * 256 + hcol;
                    const bf16x8 b2 = *(const bf16x8*)(UTb + 2 * 8192 + jb);
                    a_h[nt] = __builtin_amdgcn_mfma_f32_16x16x32_bf16(ahi, b2, a_h[nt], 0, 0, 0);
                    a_h[nt] = __builtin_amdgcn_mfma_f32_16x16x32_bf16(alo, b2, a_h[nt], 0, 0, 0);
                }
            }
#pragma unroll
            for (int nt = 0; nt < 2; ++nt) {
#pragma unroll
                for (int r = 0; r < 4; ++r) {
                    const int mrow = kq * 4 + r;
                    const int h = (nt0 + nt) * 16 + arow;
                    const size_t pb = (size_t)gnode[r] * 1536;
                    const float ph = P[pb + 512 + h];
                    const float hsht = tanhf(ph + a_h[nt][r]);
                    const float hsh = (1.f - z_sh[nt][r]) * hsp_f[nt][r] + z_sh[nt][r] * hsht;
                    if (vrow[r]) Ssh[(size_t)gnode[r] * H_DIM + h] = hsh;
                    const int ai = sidx(mrow, h);
                    const unsigned hb = bfp(hsh);
                    t_hsh_hi[ai] = (unsigned short)hb;
                    t_hsh_lo[ai] = (unsigned short)bfp(hsh - __uint_as_float(hb << 16));
                }
            }
            __syncthreads();

            // ================= stage 3: r_ru, z_ru =================
            f32x4 er[2], ez[2], fr[2], fz[2];
#pragma unroll
            for (int nt = 0; nt < 2; ++nt) {
                er[nt] = (f32x4){0.f, 0.f, 0.f, 0.f};
                ez[nt] = (f32x4){0.f, 0.f, 0.f, 0.f};
                fr[nt] = (f32x4){0.f, 0.f, 0.f, 0.f};
                fz[nt] = (f32x4){0.f, 0.f, 0.f, 0.f};
            }
#pragma unroll
            for (int ks = 0; ks < 8; ++ks) {
                const int ai = sidx(arow, ks * 32 + kq * 8);
                const bf16x8 rhi = *(const bf16x8*)&t_hrp_hi[ai];
                const bf16x8 rlo = *(const bf16x8*)&t_hrp_lo[ai];
                const bf16x8 shi = *(const bf16x8*)&t_hsh_hi[ai];
                const bf16x8 slo = *(const bf16x8*)&t_hsh_lo[ai];
#pragma unroll
                for (int nt = 0; nt < 2; ++nt) {
                    const int hcol = (nt0 + nt) * 16 + arow;
                    const size_t jb = (size_t)(ks * 4 + kq) * 256 + hcol;
                    const bf16x8 b3 = *(const bf16x8*)(UTb + 3 * 8192 + jb);
                    const bf16x8 b4 = *(const bf16x8*)(UTb + 4 * 8192 + jb);
                    const bf16x8 b6 = *(const bf16x8*)(UTb + 6 * 8192 + jb);
                    const bf16x8 b7 = *(const bf16x8*)(UTb + 7 * 8192 + jb);
                    er[nt] = __builtin_amdgcn_mfma_f32_16x16x32_bf16(rhi, b3, er[nt], 0, 0, 0);
                    er[nt] = __builtin_amdgcn_mfma_f32_16x16x32_bf16(rlo, b3, er[nt], 0, 0, 0);
                    ez[nt] = __builtin_amdgcn_mfma_f32_16x16x32_bf16(rhi, b4, ez[nt], 0, 0, 0);
                    ez[nt] = __builtin_amdgcn_mfma_f32_16x16x32_bf16(rlo, b4, ez[nt], 0, 0, 0);
                    fr[nt] = __builtin_amdgcn_mfma_f32_16x16x32_bf16(shi, b6, fr[nt], 0, 0, 0);
                    fr[nt] = __builtin_amdgcn_mfma_f32_16x16x32_bf16(slo, b6, fr[nt], 0, 0, 0);
                    fz[nt] = __builtin_amdgcn_mfma_f32_16x16x32_bf16(shi, b7, fz[nt], 0, 0, 0);
                    fz[nt] = __builtin_amdgcn_mfma_f32_16x16x32_bf16(slo, b7, fz[nt], 0, 0, 0);
                }
            }
            float z_ru[2][4], hrp_f[2][4];
#pragma unroll
            for (int nt = 0; nt < 2; ++nt) {
#pragma unroll
                for (int r = 0; r < 4; ++r) {
                    const int mrow = kq * 4 + r;
                    const int h = (nt0 + nt) * 16 + arow;
                    const size_t pb = (size_t)gnode[r] * 1536;
                    const float pru = P[pb + 768 + h];
                    const float pzu = P[pb + 1024 + h];
                    const int ai = sidx(mrow, h);
                    const float hrp = u16f(t_hrp_hi[ai]) + u16f(t_hrp_lo[ai]);
                    const float rru = sigmoidf_(pru + er[nt][r] + fr[nt][r]);
                    const float zru = sigmoidf_(pzu + ez[nt][r] + fz[nt][r]);
                    const float v2 = hrp * rru;
                    z_ru[nt][r] = zru;
                    hrp_f[nt][r] = hrp;
                    const unsigned hb = bfp(v2);
                    t_v2_hi[ai] = (unsigned short)hb;
                    t_v2_lo[ai] = (unsigned short)bfp(v2 - __uint_as_float(hb << 16));
                }
            }
            __syncthreads();

            // ================= stage 4: h_ru =================
            f32x4 eh[2], fh[2];
#pragma unroll
            for (int nt = 0; nt < 2; ++nt) {
                eh[nt] = (f32x4){0.f, 0.f, 0.f, 0.f};
                fh[nt] = (f32x4){0.f, 0.f, 0.f, 0.f};
            }
#pragma unroll
            for (int ks = 0; ks < 8; ++ks) {
                const int ai = sidx(arow, ks * 32 + kq * 8);
                const bf16x8 vhi = *(const bf16x8*)&t_v2_hi[ai];
                const bf16x8 vlo = *(const bf16x8*)&t_v2_lo[ai];
                const bf16x8 shi = *(const bf16x8*)&t_hsh_hi[ai];
                const bf16x8 slo = *(const bf16x8*)&t_hsh_lo[ai];
#pragma unroll
                for (int nt = 0; nt < 2; ++nt) {
                    const int hcol = (nt0 + nt) * 16 + arow;
                    const size_t jb = (size_t)(ks * 4 + kq) * 256 + hcol;
                    const bf16x8 b5 = *(const bf16x8*)(UTb + 5 * 8192 + jb);
                    const bf16x8 b8 = *(const bf16x8*)(UTb + 8 * 8192 + jb);
                    eh[nt] = __builtin_amdgcn_mfma_f32_16x16x32_bf16(vhi, b5, eh[nt], 0, 0, 0);
                    eh[nt] = __builtin_amdgcn_mfma_f32_16x16x32_bf16(vlo, b5, eh[nt], 0, 0, 0);
                    fh[nt] = __builtin_amdgcn_mfma_f32_16x16x32_bf16(shi, b8, fh[nt], 0, 0, 0);
                    fh[nt] = __builtin_amdgcn_mfma_f32_16x16x32_bf16(slo, b8, fh[nt], 0, 0, 0);
                }
            }
#pragma unroll
            for (int nt = 0; nt < 2; ++nt) {
#pragma unroll
                for (int r = 0; r < 4; ++r) {
                    const int h = (nt0 + nt) * 16 + arow;
                    const size_t pb = (size_t)gnode[r] * 1536;
                    const float phu = P[pb + 1280 + h];
                    const float hrut = tanhf(phu + eh[nt][r] + fh[nt][r]);
                    const float hru = (1.f - z_ru[nt][r]) * hrp_f[nt][r] + z_ru[nt][r] * hrut;
                    if (vrow[r]) {
                        Sru[(size_t)gnode[r] * H_DIM + h] = hru;
                        if (is_leaf[gnode[r]] != 0) {
                            if (nt == 0) runmax0 = fmaxf(runmax0, hru);
                            else         runmax1 = fmaxf(runmax1, hru);
                        }
                    }
                }
            }
            __syncthreads();   // tiles/levels reuse LDS; also drains Ssh/Sru stores
        }
    }

    // ---- fused epilogue: leaf-max -> logits -> softmax ----
    runmax0 = fmaxf(runmax0, __shfl_xor(runmax0, 16));
    runmax0 = fmaxf(runmax0, __shfl_xor(runmax0, 32));
    runmax1 = fmaxf(runmax1, __shfl_xor(runmax1, 16));
    runmax1 = fmaxf(runmax1, __shfl_xor(runmax1, 32));
    if (kq == 0) {
        hm[nt0 * 16 + arow] = runmax0;
        hm[(nt0 + 1) * 16 + arow] = runmax1;
    }
    __syncthreads();
    if (tid < 4) {
        float acc = br[tid];
#pragma unroll 8
        for (int j = 0; j < H_DIM; ++j) acc = fmaf(Vr[tid * 256 + j], hm[j], acc);
        lg[tid] = acc;
    }
    __syncthreads();
    if (tid == 0) {
        const float mx = fmaxf(fmaxf(lg[0], lg[1]), fmaxf(lg[2], lg[3]));
        const float e0 = expf(lg[0] - mx);
        const float e1 = expf(lg[1] - mx);
        const float e2 = expf(lg[2] - mx);
        const float e3 = expf(lg[3] - mx);
        const float s = e0 + e1 + e2 + e3;
        out[tree * 4 + 0] = e0 / s;
        out[tree * 4 + 1] = e1 / s;
        out[tree * 4 + 2] = e2 / s;
        out[tree * 4 + 3] = e3 / s;
    }
}

extern "C" void kernel_launch(void* const* d_in, const int* in_sizes, int n_in,
                              void* d_out, int out_size, void* d_ws, size_t ws_size,
                              hipStream_t stream) {
    const float* x      = (const float*)d_in[0];
    const float* Er     = (const float*)d_in[1];
    const float* Wsr_r  = (const float*)d_in[2];
    const float* Usr_r  = (const float*)d_in[3];
    const float* Wsr_z  = (const float*)d_in[4];
    const float* Usr_z  = (const float*)d_in[5];
    const float* Wsr_h  = (const float*)d_in[6];
    const float* Usr_h  = (const float*)d_in[7];
    const float* Wr_r   = (const float*)d_in[8];
    const float* Ur_r   = (const float*)d_in[9];
    const float* Usr2r_r= (const float*)d_in[10];
    const float* Wr_z   = (const float*)d_in[11];
    const float* Ur_z   = (const float*)d_in[12];
    const float* Usr2r_z= (const float*)d_in[13];
    const float* Wr_h   = (const float*)d_in[14];
    const float* Ur_h   = (const float*)d_in[15];
    const float* Usr2r_h= (const float*)d_in[16];
    const float* Vr     = (const float*)d_in[17];
    const float* br     = (const float*)d_in[18];
    const int*   parents= (const int*)d_in[19];
    const int*   is_leaf= (const int*)d_in[20];
    float* out = (float*)d_out;

    float* ws = (float*)d_ws;
    float* xt   = ws;                          // 4096*256  f32
    float* P    = xt + 1048576;                // 4096*1536 f32
    float* Wcat = P + 6291456;                 // 1536*256  f32
    uint4* UTb  = (uint4*)(Wcat + 393216);     // 9*32*256 uint4
    float* Ssh  = (float*)(UTb + 73728);       // 32*128*256 f32
    float* Sru  = Ssh + 1048576;               // 32*128*256 f32
    int*   schedT = (int*)(Sru + 1048576);     // 32*128 ints
    int*   loffT  = schedT + B_TREES * N_NODES; // 32*132 ints

    dim3 blk(256);

    // 1) x_tilde = x @ Er^T   (M=4096, N=256, K=5000) — MFMA bf16
    gemm_mfma_nt<<<dim3(64, 4), blk, 0, stream>>>(x, Er, xt, 5000, 256);

    // 2) Wcat = concat(W) rows; P = xt @ Wcat^T (M=4096, N=1536, K=256)
    const float* Ws6[6] = {Wsr_r, Wsr_z, Wsr_h, Wr_r, Wr_z, Wr_h};
    for (int w = 0; w < 6; ++w)
        (void)hipMemcpyAsync(Wcat + (size_t)w * 65536, Ws6[w],
                             65536 * sizeof(float), hipMemcpyDeviceToDevice,
                             stream);
    gemm_mfma_nt<<<dim3(64, 24), blk, 0, stream>>>(xt, Wcat, P, 256, 1536);

    // 3) bf16-pack transposed U
    transpose_pack_u<<<dim3(32, 9), blk, 0, stream>>>(
        Usr_r, Usr_z, Usr_h, Ur_r, Ur_z, Ur_h, Usr2r_r, Usr2r_z, Usr2r_h, UTb);

    // 4) per-tree level schedules
    build_schedule_t<<<dim3(1), dim3(64), 0, stream>>>(parents, schedT, loffT);

    // 5) tree-parallel MFMA scan with fused epilogue (plain launch, no sync)
    tree_scan_mfma<<<dim3(B_TREES), dim3(512), 0, stream>>>(
        P, UTb, parents, schedT, loffT, is_leaf, Vr, br, Ssh, Sru, out);
}

// Round 4
// 992.029 us; speedup vs baseline: 2.1957x; 2.1957x over previous
//
#include <hip/hip_runtime.h>
#include <hip/hip_bf16.h>
#include <math.h>

// ---------------------------------------------------------------------------
// B=32, N=128, D=5000, H=256, C=4
//   1) x_tilde = x @ Er^T            (MFMA bf16 NT gemm, fp32 in/out)
//   2) Wcat = concat 6 W (d2d memcpy); P = x_tilde @ Wcat^T (one MFMA gemm)
//   3) UTb = bf16-packed transposed U
//   4) build_schedule: level schedule + TPB-group table + zeroed ready flags
//   5) tree_scan_df (R11): R2/R9's proven VALU body, but DATAFLOW sync:
//      per-node ready flags at the coherence point replace the global
//      barrier. Groups of TPB=4 schedule-consecutive nodes (group
//      boundaries respect levels -> a group's parents are in strictly
//      earlier groups -> acyclic -> deadlock-free). WG w runs groups
//      w, w+256, ... in order; polls parent flags before, sets flags after.
//      No grid barrier, no straggler sync: scan time ~ critical path
//      (depth x body) instead of levels x (straggler + barrier).
//      R3 lesson: MFMA/one-WG-per-tree blew up HBM traffic 24x (720 MB:
//      U re-streamed per 60%-padded tile + spills) at 2.5% occupancy.
//   6) epilogue
// ---------------------------------------------------------------------------

#define H_DIM 256
#define N_NODES 128
#define B_TREES 32
#define MAXL 128
#define TPB 4
#define GRID_WGS 256

typedef short bf16x8 __attribute__((ext_vector_type(8)));
typedef float f32x4 __attribute__((ext_vector_type(4)));

__device__ __forceinline__ float sigmoidf_(float x) {
    return 1.0f / (1.0f + expf(-x));
}
__device__ __forceinline__ unsigned bfp(float x) {  // fp32 -> bf16 bits (RNE)
    unsigned u = __float_as_uint(x);
    return (u + 0x7fffu + ((u >> 16) & 1u)) >> 16;
}
__device__ __forceinline__ float bflo(unsigned w) { return __uint_as_float(w << 16); }
__device__ __forceinline__ float bfhi(unsigned w) { return __uint_as_float(w & 0xffff0000u); }

__device__ __forceinline__ void unpack8(uint4 v, float* f) {
    f[0] = bflo(v.x); f[1] = bfhi(v.x);
    f[2] = bflo(v.y); f[3] = bfhi(v.y);
    f[4] = bflo(v.z); f[5] = bfhi(v.z);
    f[6] = bflo(v.w); f[7] = bfhi(v.w);
}

// Coherent (device-scope, relaxed) accessors — read/write at the coherence
// point with NO cache-maintenance fences and NO RMW serialization.
__device__ __forceinline__ float coh_load(const float* p) {
    return __hip_atomic_load(p, __ATOMIC_RELAXED, __HIP_MEMORY_SCOPE_AGENT);
}
__device__ __forceinline__ void coh_store(float* p, float v) {
    __hip_atomic_store(p, v, __ATOMIC_RELAXED, __HIP_MEMORY_SCOPE_AGENT);
}
__device__ __forceinline__ unsigned coh_loadu(const unsigned* p) {
    return __hip_atomic_load(p, __ATOMIC_RELAXED, __HIP_MEMORY_SCOPE_AGENT);
}
__device__ __forceinline__ void coh_storeu(unsigned* p, unsigned v) {
    __hip_atomic_store(p, v, __ATOMIC_RELAXED, __HIP_MEMORY_SCOPE_AGENT);
}

// ---------------------------------------------------------------------------
// MFMA bf16 NT GEMM: C[M,N] = A[M,K] @ B[N,K]^T, fp32 in/out, bf16 compute.
// 64x64 tile, 256 thr (4 waves). Verified fragment maps (learn_hip m89/m120).
// ---------------------------------------------------------------------------
__global__ __launch_bounds__(256) void gemm_mfma_nt(
    const float* __restrict__ A, const float* __restrict__ B,
    float* __restrict__ C, int K, int ldc) {
    __shared__ short As[64][40];
    __shared__ short Bs[64][40];
    const int tid = threadIdx.x;
    const int bm = blockIdx.x, bn = blockIdx.y;
    const int row = tid >> 2;
    const int quad = tid & 3;
    const int wave = tid >> 6;
    const int lane = tid & 63;
    const int lm = lane & 15;
    const int kq = lane >> 4;

    f32x4 acc[4];
#pragma unroll
    for (int i = 0; i < 4; ++i) acc[i] = (f32x4){0.f, 0.f, 0.f, 0.f};

    const int nk = (K + 31) >> 5;
    for (int kt = 0; kt < nk; ++kt) {
        const int k0 = kt << 5;
        const int kbase = k0 + quad * 8;
        {
            float a8[8];
            const float* Ap = A + (size_t)(bm * 64 + row) * K + kbase;
            if (kbase + 8 <= K) {
                const float4 v0 = *(const float4*)Ap;
                const float4 v1 = *(const float4*)(Ap + 4);
                a8[0] = v0.x; a8[1] = v0.y; a8[2] = v0.z; a8[3] = v0.w;
                a8[4] = v1.x; a8[5] = v1.y; a8[6] = v1.z; a8[7] = v1.w;
            } else {
#pragma unroll
                for (int i = 0; i < 8; ++i)
                    a8[i] = (kbase + i < K) ? Ap[i] : 0.f;
            }
            uint4 v;
            v.x = bfp(a8[0]) | (bfp(a8[1]) << 16);
            v.y = bfp(a8[2]) | (bfp(a8[3]) << 16);
            v.z = bfp(a8[4]) | (bfp(a8[5]) << 16);
            v.w = bfp(a8[6]) | (bfp(a8[7]) << 16);
            *(uint4*)&As[row][quad * 8] = v;
        }
        {
            float b8[8];
            const float* Bp = B + (size_t)(bn * 64 + row) * K + kbase;
            if (kbase + 8 <= K) {
                const float4 v0 = *(const float4*)Bp;
                const float4 v1 = *(const float4*)(Bp + 4);
                b8[0] = v0.x; b8[1] = v0.y; b8[2] = v0.z; b8[3] = v0.w;
                b8[4] = v1.x; b8[5] = v1.y; b8[6] = v1.z; b8[7] = v1.w;
            } else {
#pragma unroll
                for (int i = 0; i < 8; ++i)
                    b8[i] = (kbase + i < K) ? Bp[i] : 0.f;
            }
            uint4 v;
            v.x = bfp(b8[0]) | (bfp(b8[1]) << 16);
            v.y = bfp(b8[2]) | (bfp(b8[3]) << 16);
            v.z = bfp(b8[4]) | (bfp(b8[5]) << 16);
            v.w = bfp(b8[6]) | (bfp(b8[7]) << 16);
            *(uint4*)&Bs[row][quad * 8] = v;
        }
        __syncthreads();
        const bf16x8 af = *(const bf16x8*)&As[wave * 16 + lm][kq * 8];
#pragma unroll
        for (int nt = 0; nt < 4; ++nt) {
            const bf16x8 bf = *(const bf16x8*)&Bs[nt * 16 + lm][kq * 8];
            acc[nt] = __builtin_amdgcn_mfma_f32_16x16x32_bf16(af, bf, acc[nt], 0, 0, 0);
        }
        __syncthreads();
    }
#pragma unroll
    for (int nt = 0; nt < 4; ++nt) {
#pragma unroll
        for (int r = 0; r < 4; ++r) {
            const int gm = bm * 64 + wave * 16 + kq * 4 + r;
            const int gn = bn * 64 + nt * 16 + lm;
            C[(size_t)gm * ldc + gn] = acc[nt][r];
        }
    }
}

// UTb[(m*32 + jblk)*256 + h] = uint4 of 8 bf16 = U_m[h][8*jblk .. 8*jblk+7]
__global__ __launch_bounds__(256) void transpose_pack_u(
    const float* __restrict__ U0, const float* __restrict__ U1,
    const float* __restrict__ U2, const float* __restrict__ U3,
    const float* __restrict__ U4, const float* __restrict__ U5,
    const float* __restrict__ U6, const float* __restrict__ U7,
    const float* __restrict__ U8, uint4* __restrict__ UTb) {
    const float* Us[9] = {U0, U1, U2, U3, U4, U5, U6, U7, U8};
    const int jb = blockIdx.x;
    const int m = blockIdx.y;
    const int h = threadIdx.x;
    const float* U = Us[m] + (size_t)h * 256 + jb * 8;
    uint4 v;
    v.x = bfp(U[0]) | (bfp(U[1]) << 16);
    v.y = bfp(U[2]) | (bfp(U[3]) << 16);
    v.z = bfp(U[4]) | (bfp(U[5]) << 16);
    v.w = bfp(U[6]) | (bfp(U[7]) << 16);
    UTb[(size_t)(m * 32 + jb) * 256 + h] = v;
}

// Level schedule + TPB-group table (group boundaries respect levels) +
// zeroed ready flags.
__global__ __launch_bounds__(256) void build_schedule(
    const int* __restrict__ parents, int* __restrict__ sched,
    int* __restrict__ level_off, int* __restrict__ gstart,
    int* __restrict__ gend, int* __restrict__ ngrp,
    unsigned* __restrict__ ready) {
    __shared__ unsigned char depth[B_TREES][N_NODES];
    __shared__ int counts[MAXL];
    __shared__ int base[MAXL + 1];
    const int tid = threadIdx.x;
    // zero ready flags at the coherence point
    for (int k = tid; k < B_TREES * N_NODES; k += 256)
        coh_storeu(&ready[k], 0u);
    for (int k = tid; k < MAXL; k += 256) counts[k] = 0;
    __syncthreads();
    if (tid < B_TREES) {
        depth[tid][0] = 0;
        for (int i = 1; i < N_NODES; ++i) {
            const int p = parents[tid * N_NODES + i];
            depth[tid][i] = (unsigned char)(depth[tid][p - 1] + 1);
        }
    }
    __syncthreads();
    for (int k = tid; k < B_TREES * N_NODES; k += 256)
        atomicAdd(&counts[depth[k >> 7][k & 127]], 1);
    __syncthreads();
    if (tid == 0) {
        int acc = 0;
        int nl = 0;
        for (int l = 0; l < MAXL; ++l) {
            base[l] = acc;
            acc += counts[l];
            if (counts[l] > 0) nl = l + 1;
        }
        base[MAXL] = acc;
        level_off[MAXL + 1] = nl;
        // group table: chunks of TPB within each level
        int ng = 0;
        for (int l = 0; l < nl; ++l) {
            for (int s = base[l]; s < base[l + 1]; s += TPB) {
                gstart[ng] = s;
                gend[ng] = (s + TPB < base[l + 1]) ? s + TPB : base[l + 1];
                ++ng;
            }
        }
        *ngrp = ng;
    }
    __syncthreads();
    for (int k = tid; k <= MAXL; k += 256) level_off[k] = base[k];
    for (int k = tid; k < MAXL; k += 256) counts[k] = 0;
    __syncthreads();
    for (int k = tid; k < B_TREES * N_NODES; k += 256) {
        const int d = depth[k >> 7][k & 127];
        const int pos = base[d] + atomicAdd(&counts[d], 1);
        sched[pos] = k;
    }
}

// Dataflow tree GRU — R2's proven body, per-node ready-flag sync (R11).
__global__ __launch_bounds__(256, 1) void tree_scan_df(
    const float* __restrict__ P, const uint4* __restrict__ UTb,
    const int* __restrict__ parents,
    const int* __restrict__ sched,
    const int* __restrict__ gstart, const int* __restrict__ gend,
    const int* __restrict__ ngrp, unsigned* __restrict__ ready,
    float* __restrict__ Ssh, float* __restrict__ Sru) {
    const int h = threadIdx.x;
    const int wg = blockIdx.x;
    __shared__ float hsp_s[H_DIM][TPB];
    __shared__ float hrp_s[H_DIM][TPB];
    __shared__ float aux_s[H_DIM][TPB];
    __shared__ float hsh_s[H_DIM][TPB];

    const uint4* __restrict__ U0b = UTb + 0 * 8192;
    const uint4* __restrict__ U1b = UTb + 1 * 8192;
    const uint4* __restrict__ U2b = UTb + 2 * 8192;
    const uint4* __restrict__ U3b = UTb + 3 * 8192;
    const uint4* __restrict__ U4b = UTb + 4 * 8192;
    const uint4* __restrict__ U5b = UTb + 5 * 8192;
    const uint4* __restrict__ U6b = UTb + 6 * 8192;
    const uint4* __restrict__ U7b = UTb + 7 * 8192;
    const uint4* __restrict__ U8b = UTb + 8 * 8192;

    const int ng = ngrp[0];
    for (int g = wg; g < ng; g += GRID_WGS) {
        const int s = gstart[g];
        const int e = gend[g];
        // ---- wait for parents (read-only coherent polls; group's parents
        //      are in strictly earlier groups -> acyclic -> no deadlock) ----
        if (h == 0) {
            for (int i = s; i < e; ++i) {
                const int nd = sched[i];
                const int p = parents[nd];
                if (p != 0) {
                    const unsigned* f = &ready[(nd & ~127) + p - 1];
                    while (coh_loadu(f) == 0u) __builtin_amdgcn_s_sleep(2);
                }
            }
        }
        __syncthreads();

        int  node[TPB];
        bool val[TPB];
        float phs[TPB], phr[TPB];
#pragma unroll
        for (int t = 0; t < TPB; ++t) {
            const int idx = s + t;
            val[t] = idx < e;
            const int nd = val[t] ? sched[idx] : sched[s];
            node[t] = nd;
            const int p = parents[nd];
            float hs = 0.f, hr = 0.f;
            if (p != 0) {
                const size_t pr = ((size_t)((nd & ~127) + p - 1)) * H_DIM + h;
                hs = coh_load(&Ssh[pr]);
                hr = coh_load(&Sru[pr]);
            }
            phs[t] = hs;
            phr[t] = hr;
        }
        *(float4*)&hsp_s[h][0] = make_float4(phs[0], phs[1], phs[2], phs[3]);
        *(float4*)&hrp_s[h][0] = make_float4(phr[0], phr[1], phr[2], phr[3]);
        __syncthreads();

        // ---------------- stage 1: r_sh, z_sh ----------------
        float pr_[TPB], pz_[TPB];
#pragma unroll
        for (int t = 0; t < TPB; ++t) {
            const float* Pi = P + (size_t)node[t] * 1536;
            pr_[t] = Pi[h];
            pz_[t] = Pi[256 + h];
        }
        float dr[TPB] = {0.f, 0.f, 0.f, 0.f};
        float dz[TPB] = {0.f, 0.f, 0.f, 0.f};
#pragma unroll 4
        for (int jb = 0; jb < 32; ++jb) {
            const uint4 w0 = U0b[jb * 256 + h];
            const uint4 w1 = U1b[jb * 256 + h];
            float a[8], c[8];
            unpack8(w0, a);
            unpack8(w1, c);
#pragma unroll
            for (int q = 0; q < 8; ++q) {
                const float4 hv = *(const float4*)&hsp_s[jb * 8 + q][0];
                const float hv4[4] = {hv.x, hv.y, hv.z, hv.w};
#pragma unroll
                for (int t = 0; t < TPB; ++t) {
                    dr[t] = fmaf(a[q], hv4[t], dr[t]);
                    dz[t] = fmaf(c[q], hv4[t], dz[t]);
                }
            }
        }
        float z_sh[TPB], vsh[TPB];
#pragma unroll
        for (int t = 0; t < TPB; ++t) {
            const float r_sh = sigmoidf_(pr_[t] + dr[t]);
            z_sh[t] = sigmoidf_(pz_[t] + dz[t]);
            vsh[t] = phs[t] * r_sh;
        }
        *(float4*)&aux_s[h][0] = make_float4(vsh[0], vsh[1], vsh[2], vsh[3]);
        __syncthreads();

        // ---------------- stage 2: h_sh ----------------
        float ph_[TPB];
#pragma unroll
        for (int t = 0; t < TPB; ++t)
            ph_[t] = P[(size_t)node[t] * 1536 + 512 + h];
        float dh[TPB] = {0.f, 0.f, 0.f, 0.f};
#pragma unroll 8
        for (int jb = 0; jb < 32; ++jb) {
            const uint4 w2 = U2b[jb * 256 + h];
            float a[8];
            unpack8(w2, a);
#pragma unroll
            for (int q = 0; q < 8; ++q) {
                const float4 hv = *(const float4*)&aux_s[jb * 8 + q][0];
                const float hv4[4] = {hv.x, hv.y, hv.z, hv.w};
#pragma unroll
                for (int t = 0; t < TPB; ++t)
                    dh[t] = fmaf(a[q], hv4[t], dh[t]);
            }
        }
        float hsh[TPB];
#pragma unroll
        for (int t = 0; t < TPB; ++t) {
            const float hsh_t = tanhf(ph_[t] + dh[t]);
            hsh[t] = (1.f - z_sh[t]) * phs[t] + z_sh[t] * hsh_t;
            if (val[t])
                coh_store(&Ssh[(size_t)node[t] * H_DIM + h], hsh[t]);
        }
        *(float4*)&hsh_s[h][0] = make_float4(hsh[0], hsh[1], hsh[2], hsh[3]);
        __syncthreads();

        // ---------------- stage 3: r_ru, z_ru ----------------
        float pru_[TPB], pzu_[TPB];
#pragma unroll
        for (int t = 0; t < TPB; ++t) {
            const float* Pi = P + (size_t)node[t] * 1536;
            pru_[t] = Pi[768 + h];
            pzu_[t] = Pi[1024 + h];
        }
        float er[TPB] = {0.f, 0.f, 0.f, 0.f};
        float ez[TPB] = {0.f, 0.f, 0.f, 0.f};
        float fr[TPB] = {0.f, 0.f, 0.f, 0.f};
        float fz[TPB] = {0.f, 0.f, 0.f, 0.f};
#pragma unroll 2
        for (int jb = 0; jb < 32; ++jb) {
            const uint4 w3 = U3b[jb * 256 + h];
            const uint4 w4 = U4b[jb * 256 + h];
            const uint4 w6 = U6b[jb * 256 + h];
            const uint4 w7 = U7b[jb * 256 + h];
            float a3[8], a4[8], a6[8], a7[8];
            unpack8(w3, a3);
            unpack8(w4, a4);
            unpack8(w6, a6);
            unpack8(w7, a7);
#pragma unroll
            for (int q = 0; q < 8; ++q) {
                const float4 hr4 = *(const float4*)&hrp_s[jb * 8 + q][0];
                const float4 hs4 = *(const float4*)&hsh_s[jb * 8 + q][0];
                const float hrv[4] = {hr4.x, hr4.y, hr4.z, hr4.w};
                const float hsv[4] = {hs4.x, hs4.y, hs4.z, hs4.w};
#pragma unroll
                for (int t = 0; t < TPB; ++t) {
                    er[t] = fmaf(a3[q], hrv[t], er[t]);
                    ez[t] = fmaf(a4[q], hrv[t], ez[t]);
                    fr[t] = fmaf(a6[q], hsv[t], fr[t]);
                    fz[t] = fmaf(a7[q], hsv[t], fz[t]);
                }
            }
        }
        float z_ru[TPB], v2[TPB];
#pragma unroll
        for (int t = 0; t < TPB; ++t) {
            const float r_ru = sigmoidf_(pru_[t] + er[t] + fr[t]);
            z_ru[t] = sigmoidf_(pzu_[t] + ez[t] + fz[t]);
            v2[t] = phr[t] * r_ru;
        }
        *(float4*)&aux_s[h][0] = make_float4(v2[0], v2[1], v2[2], v2[3]);
        __syncthreads();

        // ---------------- stage 4: h_ru ----------------
        float phu_[TPB];
#pragma unroll
        for (int t = 0; t < TPB; ++t)
            phu_[t] = P[(size_t)node[t] * 1536 + 1280 + h];
        float eh[TPB] = {0.f, 0.f, 0.f, 0.f};
        float fh[TPB] = {0.f, 0.f, 0.f, 0.f};
#pragma unroll 4
        for (int jb = 0; jb < 32; ++jb) {
            const uint4 w5 = U5b[jb * 256 + h];
            const uint4 w8 = U8b[jb * 256 + h];
            float a5[8], a8[8];
            unpack8(w5, a5);
            unpack8(w8, a8);
#pragma unroll
            for (int q = 0; q < 8; ++q) {
                const float4 v4 = *(const float4*)&aux_s[jb * 8 + q][0];
                const float4 s4 = *(const float4*)&hsh_s[jb * 8 + q][0];
                const float vv[4] = {v4.x, v4.y, v4.z, v4.w};
                const float sv[4] = {s4.x, s4.y, s4.z, s4.w};
#pragma unroll
                for (int t = 0; t < TPB; ++t) {
                    eh[t] = fmaf(a5[q], vv[t], eh[t]);
                    fh[t] = fmaf(a8[q], sv[t], fh[t]);
                }
            }
        }
#pragma unroll
        for (int t = 0; t < TPB; ++t) {
            const float hru_t = tanhf(phu_[t] + eh[t] + fh[t]);
            const float h_ru = (1.f - z_ru[t]) * phr[t] + z_ru[t] * hru_t;
            if (val[t])
                coh_store(&Sru[(size_t)node[t] * H_DIM + h], h_ru);
        }
        // drain ALL waves' coherent state stores (each wave does
        // s_waitcnt vmcnt(0) before s_barrier), THEN publish flags.
        __syncthreads();
        if (h < TPB && s + h < e)
            coh_storeu(&ready[sched[s + h]], 1u);
        __syncthreads();
    }
}

__global__ __launch_bounds__(256) void epilogue_k(
    const float* __restrict__ Sru, const int* __restrict__ is_leaf,
    const float* __restrict__ Vr, const float* __restrict__ br,
    float* __restrict__ out) {
    const int b = blockIdx.x;
    const int h = threadIdx.x;
    float m = -3.402823466e38f;
    for (int n = 0; n < N_NODES; ++n) {
        const float v = Sru[((size_t)b * N_NODES + n) * H_DIM + h];
        if (is_leaf[b * N_NODES + n] != 0) m = fmaxf(m, v);
    }
    __shared__ float hm[H_DIM];
    __shared__ float lg[4];
    hm[h] = m;
    __syncthreads();
    if (h < 4) {
        float acc = br[h];
#pragma unroll 8
        for (int j = 0; j < H_DIM; ++j) acc = fmaf(Vr[h * 256 + j], hm[j], acc);
        lg[h] = acc;
    }
    __syncthreads();
    if (h == 0) {
        const float mx = fmaxf(fmaxf(lg[0], lg[1]), fmaxf(lg[2], lg[3]));
        const float e0 = expf(lg[0] - mx);
        const float e1 = expf(lg[1] - mx);
        const float e2 = expf(lg[2] - mx);
        const float e3 = expf(lg[3] - mx);
        const float s = e0 + e1 + e2 + e3;
        out[b * 4 + 0] = e0 / s;
        out[b * 4 + 1] = e1 / s;
        out[b * 4 + 2] = e2 / s;
        out[b * 4 + 3] = e3 / s;
    }
}

extern "C" void kernel_launch(void* const* d_in, const int* in_sizes, int n_in,
                              void* d_out, int out_size, void* d_ws, size_t ws_size,
                              hipStream_t stream) {
    const float* x      = (const float*)d_in[0];
    const float* Er     = (const float*)d_in[1];
    const float* Wsr_r  = (const float*)d_in[2];
    const float* Usr_r  = (const float*)d_in[3];
    const float* Wsr_z  = (const float*)d_in[4];
    const float* Usr_z  = (const float*)d_in[5];
    const float* Wsr_h  = (const float*)d_in[6];
    const float* Usr_h  = (const float*)d_in[7];
    const float* Wr_r   = (const float*)d_in[8];
    const float* Ur_r   = (const float*)d_in[9];
    const float* Usr2r_r= (const float*)d_in[10];
    const float* Wr_z   = (const float*)d_in[11];
    const float* Ur_z   = (const float*)d_in[12];
    const float* Usr2r_z= (const float*)d_in[13];
    const float* Wr_h   = (const float*)d_in[14];
    const float* Ur_h   = (const float*)d_in[15];
    const float* Usr2r_h= (const float*)d_in[16];
    const float* Vr     = (const float*)d_in[17];
    const float* br     = (const float*)d_in[18];
    const int*   parents= (const int*)d_in[19];
    const int*   is_leaf= (const int*)d_in[20];
    float* out = (float*)d_out;

    float* ws = (float*)d_ws;
    float* xt   = ws;                          // 4096*256  f32
    float* P    = xt + 1048576;                // 4096*1536 f32
    float* Wcat = P + 6291456;                 // 1536*256  f32
    uint4* UTb  = (uint4*)(Wcat + 393216);     // 9*32*256 uint4
    float* Ssh  = (float*)(UTb + 73728);       // 32*128*256 f32
    float* Sru  = Ssh + 1048576;               // 32*128*256 f32
    int*   sched     = (int*)(Sru + 1048576);  // 4096
    int*   level_off = sched + 4096;           // 192
    unsigned* ready  = (unsigned*)(level_off + 192);  // 4096
    int*   gstart    = (int*)(ready + 4096);   // 2048
    int*   gend      = gstart + 2048;          // 2048
    int*   ngrp      = gend + 2048;            // 16

    dim3 blk(256);

    // 1) x_tilde = x @ Er^T   (M=4096, N=256, K=5000) — MFMA bf16
    gemm_mfma_nt<<<dim3(64, 4), blk, 0, stream>>>(x, Er, xt, 5000, 256);

    // 2) Wcat = concat(W) rows; P = xt @ Wcat^T (M=4096, N=1536, K=256)
    const float* Ws6[6] = {Wsr_r, Wsr_z, Wsr_h, Wr_r, Wr_z, Wr_h};
    for (int w = 0; w < 6; ++w)
        (void)hipMemcpyAsync(Wcat + (size_t)w * 65536, Ws6[w],
                             65536 * sizeof(float), hipMemcpyDeviceToDevice,
                             stream);
    gemm_mfma_nt<<<dim3(64, 24), blk, 0, stream>>>(xt, Wcat, P, 256, 1536);

    // 3) bf16-pack transposed U
    transpose_pack_u<<<dim3(32, 9), blk, 0, stream>>>(
        Usr_r, Usr_z, Usr_h, Ur_r, Ur_z, Ur_h, Usr2r_r, Usr2r_z, Usr2r_h, UTb);

    // 4) schedule + group table + zeroed flags
    build_schedule<<<dim3(1), blk, 0, stream>>>(parents, sched, level_off,
                                                gstart, gend, ngrp, ready);

    // 5) dataflow scan (cooperative launch guarantees co-residency for the
    //    flag polling; no grid.sync is used)
    void* args[] = {(void*)&P, (void*)&UTb, (void*)&parents, (void*)&sched,
                    (void*)&gstart, (void*)&gend, (void*)&ngrp, (void*)&ready,
                    (void*)&Ssh, (void*)&Sru};
    (void)hipLaunchCooperativeKernel((const void*)tree_scan_df,
                                     dim3(GRID_WGS), blk, args, 0, stream);

    // 6) epilogue
    epilogue_k<<<dim3(B_TREES), blk, 0, stream>>>(Sru, is_leaf, Vr, br, out);
}

// Round 5
// 822.528 us; speedup vs baseline: 2.6482x; 1.2061x over previous
//
#include <hip/hip_runtime.h>
#include <hip/hip_bf16.h>
#include <math.h>

// ---------------------------------------------------------------------------
// B=32, N=128, D=5000, H=256, C=4
//   1) x_tilde = x @ Er^T  — MFMA bf16 NT gemm, K-SPLIT z=4 (R12): gemm1 was
//      1 wave/SIMD with 157 serial staging iters (latency-exposed); 4 K-chunks
//      write partials into P's (free) space, reduce4_k sums into xt.
//   2) Wcat = concat 6 W; P = xt @ Wcat^T (one MFMA gemm, z=1)
//   3) UTb = bf16-packed transposed U
//   4) build_schedule: level schedule + TPB-group table + zeroed ready flags
//   5) tree_scan_df (R12): dataflow sync (R11 protocol, proven) with TPB=2:
//      - halves per-thread MACs (9216->4608; body ~11.6 -> ~7.5 us)
//      - halves the parent-join width (max-of-2, less critical-path inflation)
//      - parallel 2-lane parent poll, s_sleep(1)
//      R3 lesson: MFMA/one-WG-per-tree blew HBM 24x. R4 lesson: body is
//      issue-bound VALU; join-max inflates the 19-hop chain ~2x.
//   6) epilogue
// ---------------------------------------------------------------------------

#define H_DIM 256
#define N_NODES 128
#define B_TREES 32
#define MAXL 128
#define TPB 2
#define GRID_WGS 256

typedef short bf16x8 __attribute__((ext_vector_type(8)));
typedef float f32x4 __attribute__((ext_vector_type(4)));

__device__ __forceinline__ float sigmoidf_(float x) {
    return 1.0f / (1.0f + expf(-x));
}
__device__ __forceinline__ unsigned bfp(float x) {  // fp32 -> bf16 bits (RNE)
    unsigned u = __float_as_uint(x);
    return (u + 0x7fffu + ((u >> 16) & 1u)) >> 16;
}
__device__ __forceinline__ float bflo(unsigned w) { return __uint_as_float(w << 16); }
__device__ __forceinline__ float bfhi(unsigned w) { return __uint_as_float(w & 0xffff0000u); }

__device__ __forceinline__ void unpack8(uint4 v, float* f) {
    f[0] = bflo(v.x); f[1] = bfhi(v.x);
    f[2] = bflo(v.y); f[3] = bfhi(v.y);
    f[4] = bflo(v.z); f[5] = bfhi(v.z);
    f[6] = bflo(v.w); f[7] = bfhi(v.w);
}

// Coherent (device-scope, relaxed) accessors.
__device__ __forceinline__ float coh_load(const float* p) {
    return __hip_atomic_load(p, __ATOMIC_RELAXED, __HIP_MEMORY_SCOPE_AGENT);
}
__device__ __forceinline__ void coh_store(float* p, float v) {
    __hip_atomic_store(p, v, __ATOMIC_RELAXED, __HIP_MEMORY_SCOPE_AGENT);
}
__device__ __forceinline__ unsigned coh_loadu(const unsigned* p) {
    return __hip_atomic_load(p, __ATOMIC_RELAXED, __HIP_MEMORY_SCOPE_AGENT);
}
__device__ __forceinline__ void coh_storeu(unsigned* p, unsigned v) {
    __hip_atomic_store(p, v, __ATOMIC_RELAXED, __HIP_MEMORY_SCOPE_AGENT);
}

// ---------------------------------------------------------------------------
// MFMA bf16 NT GEMM with K-chunking: C[M,N] = A[M,K-chunk] @ B[N,K-chunk]^T.
// blockIdx.z selects K-chunk [z*Kc, min(K,(z+1)*Kc)); output to C + z*zStride.
// Verified fragment maps (learn_hip m89/m120).
// ---------------------------------------------------------------------------
__global__ __launch_bounds__(256) void gemm_mfma_nt(
    const float* __restrict__ A, const float* __restrict__ B,
    float* __restrict__ C, int K, int ldc, int Kc, int zStride) {
    __shared__ short As[64][40];
    __shared__ short Bs[64][40];
    const int tid = threadIdx.x;
    const int bm = blockIdx.x, bn = blockIdx.y;
    const int z = blockIdx.z;
    const int k_begin = z * Kc;
    const int k_end = (k_begin + Kc < K) ? (k_begin + Kc) : K;
    float* Cz = C + (size_t)z * zStride;
    const int row = tid >> 2;
    const int quad = tid & 3;
    const int wave = tid >> 6;
    const int lane = tid & 63;
    const int lm = lane & 15;
    const int kq = lane >> 4;

    f32x4 acc[4];
#pragma unroll
    for (int i = 0; i < 4; ++i) acc[i] = (f32x4){0.f, 0.f, 0.f, 0.f};

    for (int k0 = k_begin; k0 < k_end; k0 += 32) {
        const int kbase = k0 + quad * 8;
        {
            float a8[8];
            const float* Ap = A + (size_t)(bm * 64 + row) * K + kbase;
            if (kbase + 8 <= k_end) {
                const float4 v0 = *(const float4*)Ap;
                const float4 v1 = *(const float4*)(Ap + 4);
                a8[0] = v0.x; a8[1] = v0.y; a8[2] = v0.z; a8[3] = v0.w;
                a8[4] = v1.x; a8[5] = v1.y; a8[6] = v1.z; a8[7] = v1.w;
            } else {
#pragma unroll
                for (int i = 0; i < 8; ++i)
                    a8[i] = (kbase + i < k_end) ? Ap[i] : 0.f;
            }
            uint4 v;
            v.x = bfp(a8[0]) | (bfp(a8[1]) << 16);
            v.y = bfp(a8[2]) | (bfp(a8[3]) << 16);
            v.z = bfp(a8[4]) | (bfp(a8[5]) << 16);
            v.w = bfp(a8[6]) | (bfp(a8[7]) << 16);
            *(uint4*)&As[row][quad * 8] = v;
        }
        {
            float b8[8];
            const float* Bp = B + (size_t)(bn * 64 + row) * K + kbase;
            if (kbase + 8 <= k_end) {
                const float4 v0 = *(const float4*)Bp;
                const float4 v1 = *(const float4*)(Bp + 4);
                b8[0] = v0.x; b8[1] = v0.y; b8[2] = v0.z; b8[3] = v0.w;
                b8[4] = v1.x; b8[5] = v1.y; b8[6] = v1.z; b8[7] = v1.w;
            } else {
#pragma unroll
                for (int i = 0; i < 8; ++i)
                    b8[i] = (kbase + i < k_end) ? Bp[i] : 0.f;
            }
            uint4 v;
            v.x = bfp(b8[0]) | (bfp(b8[1]) << 16);
            v.y = bfp(b8[2]) | (bfp(b8[3]) << 16);
            v.z = bfp(b8[4]) | (bfp(b8[5]) << 16);
            v.w = bfp(b8[6]) | (bfp(b8[7]) << 16);
            *(uint4*)&Bs[row][quad * 8] = v;
        }
        __syncthreads();
        const bf16x8 af = *(const bf16x8*)&As[wave * 16 + lm][kq * 8];
#pragma unroll
        for (int nt = 0; nt < 4; ++nt) {
            const bf16x8 bf = *(const bf16x8*)&Bs[nt * 16 + lm][kq * 8];
            acc[nt] = __builtin_amdgcn_mfma_f32_16x16x32_bf16(af, bf, acc[nt], 0, 0, 0);
        }
        __syncthreads();
    }
#pragma unroll
    for (int nt = 0; nt < 4; ++nt) {
#pragma unroll
        for (int r = 0; r < 4; ++r) {
            const int gm = bm * 64 + wave * 16 + kq * 4 + r;
            const int gn = bn * 64 + nt * 16 + lm;
            Cz[(size_t)gm * ldc + gn] = acc[nt][r];
        }
    }
}

// xt = sum of 4 K-chunk partials (each 4096*256 f32, stored in P's space)
__global__ __launch_bounds__(256) void reduce4_k(
    const float* __restrict__ Pp, float* __restrict__ xt) {
    const int i = (blockIdx.x * 256 + threadIdx.x) * 4;
    const float4 a = *(const float4*)(Pp + i);
    const float4 b = *(const float4*)(Pp + 1048576 + i);
    const float4 c = *(const float4*)(Pp + 2097152 + i);
    const float4 d = *(const float4*)(Pp + 3145728 + i);
    float4 s;
    s.x = a.x + b.x + c.x + d.x;
    s.y = a.y + b.y + c.y + d.y;
    s.z = a.z + b.z + c.z + d.z;
    s.w = a.w + b.w + c.w + d.w;
    *(float4*)(xt + i) = s;
}

// UTb[(m*32 + jblk)*256 + h] = uint4 of 8 bf16 = U_m[h][8*jblk .. 8*jblk+7]
__global__ __launch_bounds__(256) void transpose_pack_u(
    const float* __restrict__ U0, const float* __restrict__ U1,
    const float* __restrict__ U2, const float* __restrict__ U3,
    const float* __restrict__ U4, const float* __restrict__ U5,
    const float* __restrict__ U6, const float* __restrict__ U7,
    const float* __restrict__ U8, uint4* __restrict__ UTb) {
    const float* Us[9] = {U0, U1, U2, U3, U4, U5, U6, U7, U8};
    const int jb = blockIdx.x;
    const int m = blockIdx.y;
    const int h = threadIdx.x;
    const float* U = Us[m] + (size_t)h * 256 + jb * 8;
    uint4 v;
    v.x = bfp(U[0]) | (bfp(U[1]) << 16);
    v.y = bfp(U[2]) | (bfp(U[3]) << 16);
    v.z = bfp(U[4]) | (bfp(U[5]) << 16);
    v.w = bfp(U[6]) | (bfp(U[7]) << 16);
    UTb[(size_t)(m * 32 + jb) * 256 + h] = v;
}

// Level schedule + TPB-group table (group boundaries respect levels) +
// zeroed ready flags.
__global__ __launch_bounds__(256) void build_schedule(
    const int* __restrict__ parents, int* __restrict__ sched,
    int* __restrict__ level_off, int* __restrict__ gstart,
    int* __restrict__ gend, int* __restrict__ ngrp,
    unsigned* __restrict__ ready) {
    __shared__ unsigned char depth[B_TREES][N_NODES];
    __shared__ int counts[MAXL];
    __shared__ int base[MAXL + 1];
    const int tid = threadIdx.x;
    for (int k = tid; k < B_TREES * N_NODES; k += 256)
        coh_storeu(&ready[k], 0u);
    for (int k = tid; k < MAXL; k += 256) counts[k] = 0;
    __syncthreads();
    if (tid < B_TREES) {
        depth[tid][0] = 0;
        for (int i = 1; i < N_NODES; ++i) {
            const int p = parents[tid * N_NODES + i];
            depth[tid][i] = (unsigned char)(depth[tid][p - 1] + 1);
        }
    }
    __syncthreads();
    for (int k = tid; k < B_TREES * N_NODES; k += 256)
        atomicAdd(&counts[depth[k >> 7][k & 127]], 1);
    __syncthreads();
    if (tid == 0) {
        int acc = 0;
        int nl = 0;
        for (int l = 0; l < MAXL; ++l) {
            base[l] = acc;
            acc += counts[l];
            if (counts[l] > 0) nl = l + 1;
        }
        base[MAXL] = acc;
        level_off[MAXL + 1] = nl;
        int ng = 0;
        for (int l = 0; l < nl; ++l) {
            for (int s = base[l]; s < base[l + 1]; s += TPB) {
                gstart[ng] = s;
                gend[ng] = (s + TPB < base[l + 1]) ? s + TPB : base[l + 1];
                ++ng;
            }
        }
        *ngrp = ng;
    }
    __syncthreads();
    for (int k = tid; k <= MAXL; k += 256) level_off[k] = base[k];
    for (int k = tid; k < MAXL; k += 256) counts[k] = 0;
    __syncthreads();
    for (int k = tid; k < B_TREES * N_NODES; k += 256) {
        const int d = depth[k >> 7][k & 127];
        const int pos = base[d] + atomicAdd(&counts[d], 1);
        sched[pos] = k;
    }
}

// Dataflow tree GRU — TPB=2 body, per-node ready-flag sync (R12).
__global__ __launch_bounds__(256, 1) void tree_scan_df(
    const float* __restrict__ P, const uint4* __restrict__ UTb,
    const int* __restrict__ parents,
    const int* __restrict__ sched,
    const int* __restrict__ gstart, const int* __restrict__ gend,
    const int* __restrict__ ngrp, unsigned* __restrict__ ready,
    float* __restrict__ Ssh, float* __restrict__ Sru) {
    const int h = threadIdx.x;
    const int wg = blockIdx.x;
    __shared__ float hsp_s[H_DIM][TPB];
    __shared__ float hrp_s[H_DIM][TPB];
    __shared__ float aux_s[H_DIM][TPB];
    __shared__ float hsh_s[H_DIM][TPB];

    const uint4* __restrict__ U0b = UTb + 0 * 8192;
    const uint4* __restrict__ U1b = UTb + 1 * 8192;
    const uint4* __restrict__ U2b = UTb + 2 * 8192;
    const uint4* __restrict__ U3b = UTb + 3 * 8192;
    const uint4* __restrict__ U4b = UTb + 4 * 8192;
    const uint4* __restrict__ U5b = UTb + 5 * 8192;
    const uint4* __restrict__ U6b = UTb + 6 * 8192;
    const uint4* __restrict__ U7b = UTb + 7 * 8192;
    const uint4* __restrict__ U8b = UTb + 8 * 8192;

    const int ng = ngrp[0];
    for (int g = wg; g < ng; g += GRID_WGS) {
        const int s = gstart[g];
        const int e = gend[g];
        // ---- wait for parents (parallel read-only coherent polls) ----
        if (h < e - s) {
            const int nd = sched[s + h];
            const int p = parents[nd];
            if (p != 0) {
                const unsigned* f = &ready[(nd & ~127) + p - 1];
                while (coh_loadu(f) == 0u) __builtin_amdgcn_s_sleep(1);
            }
        }
        __syncthreads();

        int  node[TPB];
        bool val[TPB];
        float phs[TPB], phr[TPB];
#pragma unroll
        for (int t = 0; t < TPB; ++t) {
            const int idx = s + t;
            val[t] = idx < e;
            const int nd = val[t] ? sched[idx] : sched[s];
            node[t] = nd;
            const int p = parents[nd];
            float hs = 0.f, hr = 0.f;
            if (p != 0) {
                const size_t pr = ((size_t)((nd & ~127) + p - 1)) * H_DIM + h;
                hs = coh_load(&Ssh[pr]);
                hr = coh_load(&Sru[pr]);
            }
            phs[t] = hs;
            phr[t] = hr;
        }
        *(float2*)&hsp_s[h][0] = make_float2(phs[0], phs[1]);
        *(float2*)&hrp_s[h][0] = make_float2(phr[0], phr[1]);
        __syncthreads();

        // ---------------- stage 1: r_sh, z_sh ----------------
        float pr_[TPB], pz_[TPB];
#pragma unroll
        for (int t = 0; t < TPB; ++t) {
            const float* Pi = P + (size_t)node[t] * 1536;
            pr_[t] = Pi[h];
            pz_[t] = Pi[256 + h];
        }
        float dr[TPB] = {0.f, 0.f};
        float dz[TPB] = {0.f, 0.f};
#pragma unroll 4
        for (int jb = 0; jb < 32; ++jb) {
            const uint4 w0 = U0b[jb * 256 + h];
            const uint4 w1 = U1b[jb * 256 + h];
            float a[8], c[8];
            unpack8(w0, a);
            unpack8(w1, c);
#pragma unroll
            for (int q = 0; q < 8; ++q) {
                const float2 hv = *(const float2*)&hsp_s[jb * 8 + q][0];
                dr[0] = fmaf(a[q], hv.x, dr[0]);
                dr[1] = fmaf(a[q], hv.y, dr[1]);
                dz[0] = fmaf(c[q], hv.x, dz[0]);
                dz[1] = fmaf(c[q], hv.y, dz[1]);
            }
        }
        float z_sh[TPB], vsh[TPB];
#pragma unroll
        for (int t = 0; t < TPB; ++t) {
            const float r_sh = sigmoidf_(pr_[t] + dr[t]);
            z_sh[t] = sigmoidf_(pz_[t] + dz[t]);
            vsh[t] = phs[t] * r_sh;
        }
        *(float2*)&aux_s[h][0] = make_float2(vsh[0], vsh[1]);
        __syncthreads();

        // ---------------- stage 2: h_sh ----------------
        float ph_[TPB];
#pragma unroll
        for (int t = 0; t < TPB; ++t)
            ph_[t] = P[(size_t)node[t] * 1536 + 512 + h];
        float dh[TPB] = {0.f, 0.f};
#pragma unroll 8
        for (int jb = 0; jb < 32; ++jb) {
            const uint4 w2 = U2b[jb * 256 + h];
            float a[8];
            unpack8(w2, a);
#pragma unroll
            for (int q = 0; q < 8; ++q) {
                const float2 hv = *(const float2*)&aux_s[jb * 8 + q][0];
                dh[0] = fmaf(a[q], hv.x, dh[0]);
                dh[1] = fmaf(a[q], hv.y, dh[1]);
            }
        }
        float hsh[TPB];
#pragma unroll
        for (int t = 0; t < TPB; ++t) {
            const float hsh_t = tanhf(ph_[t] + dh[t]);
            hsh[t] = (1.f - z_sh[t]) * phs[t] + z_sh[t] * hsh_t;
            if (val[t])
                coh_store(&Ssh[(size_t)node[t] * H_DIM + h], hsh[t]);
        }
        *(float2*)&hsh_s[h][0] = make_float2(hsh[0], hsh[1]);
        __syncthreads();

        // ---------------- stage 3: r_ru, z_ru ----------------
        float pru_[TPB], pzu_[TPB];
#pragma unroll
        for (int t = 0; t < TPB; ++t) {
            const float* Pi = P + (size_t)node[t] * 1536;
            pru_[t] = Pi[768 + h];
            pzu_[t] = Pi[1024 + h];
        }
        float er[TPB] = {0.f, 0.f};
        float ez[TPB] = {0.f, 0.f};
        float fr[TPB] = {0.f, 0.f};
        float fz[TPB] = {0.f, 0.f};
#pragma unroll 2
        for (int jb = 0; jb < 32; ++jb) {
            const uint4 w3 = U3b[jb * 256 + h];
            const uint4 w4 = U4b[jb * 256 + h];
            const uint4 w6 = U6b[jb * 256 + h];
            const uint4 w7 = U7b[jb * 256 + h];
            float a3[8], a4[8], a6[8], a7[8];
            unpack8(w3, a3);
            unpack8(w4, a4);
            unpack8(w6, a6);
            unpack8(w7, a7);
#pragma unroll
            for (int q = 0; q < 8; ++q) {
                const float2 hr2 = *(const float2*)&hrp_s[jb * 8 + q][0];
                const float2 hs2 = *(const float2*)&hsh_s[jb * 8 + q][0];
                er[0] = fmaf(a3[q], hr2.x, er[0]);
                er[1] = fmaf(a3[q], hr2.y, er[1]);
                ez[0] = fmaf(a4[q], hr2.x, ez[0]);
                ez[1] = fmaf(a4[q], hr2.y, ez[1]);
                fr[0] = fmaf(a6[q], hs2.x, fr[0]);
                fr[1] = fmaf(a6[q], hs2.y, fr[1]);
                fz[0] = fmaf(a7[q], hs2.x, fz[0]);
                fz[1] = fmaf(a7[q], hs2.y, fz[1]);
            }
        }
        float z_ru[TPB], v2[TPB];
#pragma unroll
        for (int t = 0; t < TPB; ++t) {
            const float r_ru = sigmoidf_(pru_[t] + er[t] + fr[t]);
            z_ru[t] = sigmoidf_(pzu_[t] + ez[t] + fz[t]);
            v2[t] = phr[t] * r_ru;
        }
        *(float2*)&aux_s[h][0] = make_float2(v2[0], v2[1]);
        __syncthreads();

        // ---------------- stage 4: h_ru ----------------
        float phu_[TPB];
#pragma unroll
        for (int t = 0; t < TPB; ++t)
            phu_[t] = P[(size_t)node[t] * 1536 + 1280 + h];
        float eh[TPB] = {0.f, 0.f};
        float fh[TPB] = {0.f, 0.f};
#pragma unroll 4
        for (int jb = 0; jb < 32; ++jb) {
            const uint4 w5 = U5b[jb * 256 + h];
            const uint4 w8 = U8b[jb * 256 + h];
            float a5[8], a8[8];
            unpack8(w5, a5);
            unpack8(w8, a8);
#pragma unroll
            for (int q = 0; q < 8; ++q) {
                const float2 v4 = *(const float2*)&aux_s[jb * 8 + q][0];
                const float2 s4 = *(const float2*)&hsh_s[jb * 8 + q][0];
                eh[0] = fmaf(a5[q], v4.x, eh[0]);
                eh[1] = fmaf(a5[q], v4.y, eh[1]);
                fh[0] = fmaf(a8[q], s4.x, fh[0]);
                fh[1] = fmaf(a8[q], s4.y, fh[1]);
            }
        }
#pragma unroll
        for (int t = 0; t < TPB; ++t) {
            const float hru_t = tanhf(phu_[t] + eh[t] + fh[t]);
            const float h_ru = (1.f - z_ru[t]) * phr[t] + z_ru[t] * hru_t;
            if (val[t])
                coh_store(&Sru[(size_t)node[t] * H_DIM + h], h_ru);
        }
        // drain ALL waves' coherent state stores, THEN publish flags.
        __syncthreads();
        if (h < e - s)
            coh_storeu(&ready[sched[s + h]], 1u);
        __syncthreads();
    }
}

__global__ __launch_bounds__(256) void epilogue_k(
    const float* __restrict__ Sru, const int* __restrict__ is_leaf,
    const float* __restrict__ Vr, const float* __restrict__ br,
    float* __restrict__ out) {
    const int b = blockIdx.x;
    const int h = threadIdx.x;
    float m = -3.402823466e38f;
    for (int n = 0; n < N_NODES; ++n) {
        const float v = Sru[((size_t)b * N_NODES + n) * H_DIM + h];
        if (is_leaf[b * N_NODES + n] != 0) m = fmaxf(m, v);
    }
    __shared__ float hm[H_DIM];
    __shared__ float lg[4];
    hm[h] = m;
    __syncthreads();
    if (h < 4) {
        float acc = br[h];
#pragma unroll 8
        for (int j = 0; j < H_DIM; ++j) acc = fmaf(Vr[h * 256 + j], hm[j], acc);
        lg[h] = acc;
    }
    __syncthreads();
    if (h == 0) {
        const float mx = fmaxf(fmaxf(lg[0], lg[1]), fmaxf(lg[2], lg[3]));
        const float e0 = expf(lg[0] - mx);
        const float e1 = expf(lg[1] - mx);
        const float e2 = expf(lg[2] - mx);
        const float e3 = expf(lg[3] - mx);
        const float s = e0 + e1 + e2 + e3;
        out[b * 4 + 0] = e0 / s;
        out[b * 4 + 1] = e1 / s;
        out[b * 4 + 2] = e2 / s;
        out[b * 4 + 3] = e3 / s;
    }
}

extern "C" void kernel_launch(void* const* d_in, const int* in_sizes, int n_in,
                              void* d_out, int out_size, void* d_ws, size_t ws_size,
                              hipStream_t stream) {
    const float* x      = (const float*)d_in[0];
    const float* Er     = (const float*)d_in[1];
    const float* Wsr_r  = (const float*)d_in[2];
    const float* Usr_r  = (const float*)d_in[3];
    const float* Wsr_z  = (const float*)d_in[4];
    const float* Usr_z  = (const float*)d_in[5];
    const float* Wsr_h  = (const float*)d_in[6];
    const float* Usr_h  = (const float*)d_in[7];
    const float* Wr_r   = (const float*)d_in[8];
    const float* Ur_r   = (const float*)d_in[9];
    const float* Usr2r_r= (const float*)d_in[10];
    const float* Wr_z   = (const float*)d_in[11];
    const float* Ur_z   = (const float*)d_in[12];
    const float* Usr2r_z= (const float*)d_in[13];
    const float* Wr_h   = (const float*)d_in[14];
    const float* Ur_h   = (const float*)d_in[15];
    const float* Usr2r_h= (const float*)d_in[16];
    const float* Vr     = (const float*)d_in[17];
    const float* br     = (const float*)d_in[18];
    const int*   parents= (const int*)d_in[19];
    const int*   is_leaf= (const int*)d_in[20];
    float* out = (float*)d_out;

    float* ws = (float*)d_ws;
    float* xt   = ws;                          // 4096*256  f32
    float* P    = xt + 1048576;                // 4096*1536 f32 (also gemm1 partials)
    float* Wcat = P + 6291456;                 // 1536*256  f32
    uint4* UTb  = (uint4*)(Wcat + 393216);     // 9*32*256 uint4
    float* Ssh  = (float*)(UTb + 73728);       // 32*128*256 f32
    float* Sru  = Ssh + 1048576;               // 32*128*256 f32
    int*   sched     = (int*)(Sru + 1048576);  // 4096
    int*   level_off = sched + 4096;           // 192
    unsigned* ready  = (unsigned*)(level_off + 192);  // 4096
    int*   gstart    = (int*)(ready + 4096);   // 4096
    int*   gend      = gstart + 4096;          // 4096
    int*   ngrp      = gend + 4096;            // 16

    dim3 blk(256);

    // 1) x_tilde = x @ Er^T (M=4096, N=256, K=5000), K-split z=4.
    //    Partials go into P's space (free until gemm2); reduce into xt.
    gemm_mfma_nt<<<dim3(64, 4, 4), blk, 0, stream>>>(x, Er, P, 5000, 256,
                                                     1280, 1048576);
    reduce4_k<<<dim3(1024), blk, 0, stream>>>(P, xt);

    // 2) Wcat = concat(W) rows; P = xt @ Wcat^T (M=4096, N=1536, K=256)
    const float* Ws6[6] = {Wsr_r, Wsr_z, Wsr_h, Wr_r, Wr_z, Wr_h};
    for (int w = 0; w < 6; ++w)
        (void)hipMemcpyAsync(Wcat + (size_t)w * 65536, Ws6[w],
                             65536 * sizeof(float), hipMemcpyDeviceToDevice,
                             stream);
    gemm_mfma_nt<<<dim3(64, 24, 1), blk, 0, stream>>>(xt, Wcat, P, 256, 1536,
                                                      256, 0);

    // 3) bf16-pack transposed U
    transpose_pack_u<<<dim3(32, 9), blk, 0, stream>>>(
        Usr_r, Usr_z, Usr_h, Ur_r, Ur_z, Ur_h, Usr2r_r, Usr2r_z, Usr2r_h, UTb);

    // 4) schedule + group table + zeroed flags
    build_schedule<<<dim3(1), blk, 0, stream>>>(parents, sched, level_off,
                                                gstart, gend, ngrp, ready);

    // 5) dataflow scan (cooperative launch guarantees co-residency for the
    //    flag polling; no grid.sync is used)
    void* args[] = {(void*)&P, (void*)&UTb, (void*)&parents, (void*)&sched,
                    (void*)&gstart, (void*)&gend, (void*)&ngrp, (void*)&ready,
                    (void*)&Ssh, (void*)&Sru};
    (void)hipLaunchCooperativeKernel((const void*)tree_scan_df,
                                     dim3(GRID_WGS), blk, args, 0, stream);

    // 6) epilogue
    epilogue_k<<<dim3(B_TREES), blk, 0, stream>>>(Sru, is_leaf, Vr, br, out);
}